// Round 1
// 167.312 us; speedup vs baseline: 1.0226x; 1.0226x over previous
//
#include <hip/hip_runtime.h>

// Problem constants
#define B_   256
#define C_   256
#define CH_  128
#define N_   196           // H*W = 14*14
#define NF4  49            // 196 floats = 49 float4 per (b,c) row
#define NROW4 12544        // C_ * NF4 float4 per batch slab
#define EPS  1e-5f

// ---------------------------------------------------------------------------
// K0: WzvTs[c][o] = alpha[o] * sum_k Wz[o,k] * Wv[k,c]
//     alpha[o] = bn_w[o] * rsqrt(bn_var[o] + eps)   (BN scale folded in)
// Block per c (grid 256), thread per o (256). Wv column c staged in LDS;
// Wz rows are L2-resident (128 KB). Writes fully coalesced.
// ---------------------------------------------------------------------------
__global__ __launch_bounds__(256) void k_wzvt(const float* __restrict__ Wz,
                                              const float* __restrict__ Wv,
                                              const float* __restrict__ bnw,
                                              const float* __restrict__ bnv,
                                              float* __restrict__ WzvTs) {
    __shared__ float sWv[CH_];
    int c = blockIdx.x;
    int o = threadIdx.x;
    if (o < CH_) sWv[o] = Wv[o * C_ + c];
    __syncthreads();
    const float4* wzrow = (const float4*)(Wz + o * CH_);
    float acc = 0.f;
    #pragma unroll
    for (int k4 = 0; k4 < CH_ / 4; k4++) {
        float4 w = wzrow[k4];
        acc += w.x * sWv[4 * k4 + 0];
        acc += w.y * sWv[4 * k4 + 1];
        acc += w.z * sWv[4 * k4 + 2];
        acc += w.w * sWv[4 * k4 + 3];
    }
    float alpha = bnw[o] * rsqrtf(bnv[o] + EPS);
    WzvTs[c * C_ + o] = acc * alpha;
}

// ---------------------------------------------------------------------------
// K1: fused per-batch kernel. One 1024-thread block per b (grid 256, 16 waves/CU).
//   Phase A: sY[c] = sum_n y[b,c,n]      (wave w reduces rows [16w,16w+16))
//   Phase B: sZ[o] = sum_c sY[c]*WzvTs[c,o] + (bn_b[o] - bn_m[o]*alpha[o])
//            (dot segmented 4-way over c across all 1024 threads)
//   Phase C: out[b,c,n] = x[b,c,n] + sZ[c]   (float4 stream, 12x1024 + tail)
// HBM traffic = y + x reads + out write only (the 154 MB floor); ysum/Zs
// never leave LDS.
// ---------------------------------------------------------------------------
__global__ __launch_bounds__(1024, 4) void k_main(const float* __restrict__ x,
                                                  const float* __restrict__ y,
                                                  const float* __restrict__ WzvTs,
                                                  const float* __restrict__ bnw,
                                                  const float* __restrict__ bnb,
                                                  const float* __restrict__ bnm,
                                                  const float* __restrict__ bnv,
                                                  float* __restrict__ out) {
    __shared__ float sY[C_];
    __shared__ float sPart[4][C_];
    __shared__ float sZ[C_];

    int b    = blockIdx.x;
    int tid  = threadIdx.x;
    int w    = tid >> 6;       // wave id 0..15
    int lane = tid & 63;

    // ---- Phase A: row sums of y[b] into sY -------------------------------
    const float4* yb = (const float4*)y + (size_t)b * NROW4;
    #pragma unroll
    for (int i = 0; i < 16; i += 4) {
        float s[4];
        #pragma unroll
        for (int j = 0; j < 4; j++) {
            int r = (w << 4) + i + j;
            float4 v = make_float4(0.f, 0.f, 0.f, 0.f);
            if (lane < NF4) v = yb[r * NF4 + lane];
            s[j] = (v.x + v.y) + (v.z + v.w);
        }
        #pragma unroll
        for (int off = 32; off > 0; off >>= 1) {
            #pragma unroll
            for (int j = 0; j < 4; j++) s[j] += __shfl_down(s[j], off, 64);
        }
        if (lane == 0) {
            #pragma unroll
            for (int j = 0; j < 4; j++) sY[(w << 4) + i + j] = s[j];
        }
    }
    __syncthreads();

    // ---- Phase B: Zs = WzvTs^T . sY + beta, segmented over 1024 threads --
    {
        int o   = tid & (C_ - 1);   // output channel
        int seg = tid >> 8;         // c-segment 0..3 (64 c's each)
        int c0  = seg * 64;
        float acc = 0.f;
        #pragma unroll 8
        for (int c = 0; c < 64; c++)
            acc += sY[c0 + c] * WzvTs[(c0 + c) * C_ + o];
        sPart[seg][o] = acc;
    }
    __syncthreads();
    if (tid < C_) {
        float z = sPart[0][tid] + sPart[1][tid] + sPart[2][tid] + sPart[3][tid];
        float alpha = bnw[tid] * rsqrtf(bnv[tid] + EPS);
        sZ[tid] = z + bnb[tid] - bnm[tid] * alpha;   // WzvTs already has alpha
    }
    __syncthreads();

    // ---- Phase C: out = x + broadcast(sZ) --------------------------------
    const float4* xb = (const float4*)x   + (size_t)b * NROW4;
    float4*       ob = (float4*)out       + (size_t)b * NROW4;
    #pragma unroll
    for (int k = 0; k < 12; k++) {
        int idx = tid + (k << 10);
        int r = idx / NF4;                 // magic-multiply
        float z = sZ[r];
        float4 v = xb[idx];
        v.x += z; v.y += z; v.z += z; v.w += z;
        ob[idx] = v;
    }
    {   // tail: 12544 - 12*1024 = 256 float4
        int idx = tid + (12 << 10);
        if (idx < NROW4) {
            int r = idx / NF4;
            float z = sZ[r];
            float4 v = xb[idx];
            v.x += z; v.y += z; v.z += z; v.w += z;
            ob[idx] = v;
        }
    }
}

extern "C" void kernel_launch(void* const* d_in, const int* in_sizes, int n_in,
                              void* d_out, int out_size, void* d_ws, size_t ws_size,
                              hipStream_t stream) {
    const float* x   = (const float*)d_in[0];
    const float* y   = (const float*)d_in[1];
    // d_in[2] = Wq, d_in[3] = Wk : dead (softmax over singleton axis == ones)
    const float* Wv  = (const float*)d_in[4];
    const float* Wz  = (const float*)d_in[5];
    const float* bnw = (const float*)d_in[6];
    const float* bnb = (const float*)d_in[7];
    const float* bnm = (const float*)d_in[8];
    const float* bnv = (const float*)d_in[9];
    float* out = (float*)d_out;

    float* WzvTs = (float*)d_ws;   // 256*256 floats (BN-scaled weight product)

    k_wzvt<<<C_, 256, 0, stream>>>(Wz, Wv, bnw, bnv, WzvTs);
    k_main<<<B_, 1024, 0, stream>>>(x, y, WzvTs, bnw, bnb, bnm, bnv, out);
}